// Round 21
// baseline (25.474 us; speedup 1.0000x reference)
//
#include <hip/hip_runtime.h>
#include <hip/hip_bf16.h>
#include <math.h>

#define NB 8
#define NL 128
#define D_ATOM 256
#define DH 32       // d_hid
#define DAB 64      // 2*d_hid
#define K1 21
#define K2 30
#define KT 51       // K1+K2
#define ROWS (NB*NL) // 1024
#define LN_EPS 1e-5f

#define OUT1_ROW (NL*K1)      // 2688 floats
#define OUT2_ROW (NL*K2)      // 3840 floats
#define STAGE_N  (OUT1_ROW + OUT2_ROW) // 6528 floats
#define WCAT 1632             // 672 + 960 els per c

typedef __attribute__((ext_vector_type(8))) short bf16x8;
typedef __attribute__((ext_vector_type(4))) float f32x4;

__device__ __forceinline__ unsigned short f2bf(float x) {
    __hip_bfloat16 h = __float2bfloat16(x);
    return *reinterpret_cast<unsigned short*>(&h);
}

// ---------------- Kernel 1: LN v3 (R20 verbatim) ----------------------------
__global__ __launch_bounds__(256) void ln_wprep_kernel(
    const float* __restrict__ z, const float* __restrict__ W_in,
    const float* __restrict__ b_in, const float* __restrict__ ln_g,
    const float* __restrict__ ln_b, const float* __restrict__ W1,
    const float* __restrict__ W2, float* __restrict__ a_ws,
    unsigned short* __restrict__ bbf, unsigned short* __restrict__ Wlin2)
{
    __shared__ float zT[D_ATOM][2];      // 2 KB: zT[i][r]
    __shared__ float red[16][2][DAB];    // 8 KB partials [p][r][col]

    const int t = threadIdx.x;
    const int w = t >> 6, l = t & 63;
    const int g = l >> 4, c4 = l & 15;
    const int row0 = blockIdx.x * 2;

    if (t < 128) {
        const int r = t >> 6, i0 = (t & 63) * 4;
        float4 v = ((const float4*)(z + (size_t)(row0 + r) * D_ATOM))[t & 63];
        zT[i0 + 0][r] = v.x; zT[i0 + 1][r] = v.y;
        zT[i0 + 2][r] = v.z; zT[i0 + 3][r] = v.w;
    }
    __syncthreads();

    float acc[2][4];
    #pragma unroll
    for (int r = 0; r < 2; ++r)
        #pragma unroll
        for (int q = 0; q < 4; ++q) acc[r][q] = 0.f;

    const int ibase = w * 64 + g * 16;
    #pragma unroll
    for (int it = 0; it < 16; ++it) {
        const int i = ibase + it;
        float4 wv = *(const float4*)&W_in[i * DAB + 4 * c4];
        float2 zv = *(const float2*)&zT[i][0];
        float wq[4] = {wv.x, wv.y, wv.z, wv.w};
        #pragma unroll
        for (int q = 0; q < 4; ++q) {
            acc[0][q] = fmaf(zv.x, wq[q], acc[0][q]);
            acc[1][q] = fmaf(zv.y, wq[q], acc[1][q]);
        }
    }
    const int p = w * 4 + g;
    #pragma unroll
    for (int r = 0; r < 2; ++r) {
        float4 v = {acc[r][0], acc[r][1], acc[r][2], acc[r][3]};
        *(float4*)&red[p][r][4 * c4] = v;
    }
    __syncthreads();

    if (t < 128) {
        const int r = t >> 6, j = t & 63;
        float a2 = b_in[j];
        #pragma unroll
        for (int pp = 0; pp < 16; ++pp) a2 += red[pp][r][j];

        float gg = 0.5f * a2 * (1.0f + erff(a2 * 0.70710678118654752f));

        float s = gg, sq = gg * gg;
        #pragma unroll
        for (int msk = 1; msk < 64; msk <<= 1) {
            s  += __shfl_xor(s,  msk, 64);
            sq += __shfl_xor(sq, msk, 64);
        }
        float mu  = s  * (1.0f / 64.0f);
        float var = sq * (1.0f / 64.0f) - mu * mu;
        float y = (gg - mu) * rsqrtf(var + LN_EPS) * ln_g[j] + ln_b[j];

        const int row = row0 + r;
        if (j < DH) {
            a_ws[row * DH + j] = y;
        } else {
            const int d = j - DH, m = row & 127, batch = row >> 7;
            bbf[batch * 4096 + ((m >> 4) << 9) +
                ((((m & 15) | ((d >> 3) << 4)) << 3) | (d & 7))] = f2bf(y);
        }
    }

    if (t < 16) {
        int pw = (int)blockIdx.x * 16 + t;      // 0..8191
        int c  = pw >> 8, t2 = pw & 255;
        unsigned short v[8];
        #pragma unroll
        for (int s2 = 0; s2 < 8; ++s2) {
            int o = s2 * 256 + t2;
            float val = 0.f;
            if (o < 672)       val = W1[c * 672 + o];
            else if (o < WCAT) val = W2[c * 960 + (o - 672)];
            v[s2] = f2bf(val);
        }
        uint4 wq;
        wq.x = (unsigned)v[0] | ((unsigned)v[1] << 16);
        wq.y = (unsigned)v[2] | ((unsigned)v[3] << 16);
        wq.z = (unsigned)v[4] | ((unsigned)v[5] << 16);
        wq.w = (unsigned)v[6] | ((unsigned)v[7] << 16);
        ((uint4*)Wlin2)[pw] = wq;
    }
}

// ---------------- Kernel 2: pair product (R13/R17 verbatim — best) ----------
__global__ __launch_bounds__(256, 4) void pair_kernel(
    const float* __restrict__ a_ws, const unsigned short* __restrict__ bbf,
    const unsigned short* __restrict__ Wlin2, const float* __restrict__ b1v,
    const float* __restrict__ b2v, float* __restrict__ out)
{
    const int row0  = blockIdx.x * 2;
    const int batch = row0 >> 7;
    const int t     = threadIdx.x;
    const int w  = t >> 6, l = t & 63;
    const int lg = l >> 4, li = l & 15;

    __shared__ unsigned short Tf[2 * 4 * 64 * 8];    // 8 KB
    __shared__ __align__(16) float stg[STAGE_N];     // 25.5 KB (one row)
    __shared__ float al[2][DH];

    #pragma unroll
    for (int s = 0; s < 8; ++s)
        ((unsigned int*)Tf)[t + s * 256] = 0u;       // pads k=51..63 stay 0
    if (t < 2 * DH) al[t >> 5][t & 31] = a_ws[row0 * DH + t];
    __syncthreads();

    // ---- phase 1: T GEMV (uint4-packed Wlin2) ----
    {
        float tacc0[7], tacc1[7];
        int fidx[7];
        bool val[7];
        #pragma unroll
        for (int s = 0; s < 7; ++s) {
            int o = t + s * 256;
            val[s] = (o < WCAT);
            int oo = val[s] ? o : 0;
            int d, k;
            if (oo < 672) { d = oo / 21; k = oo % 21; }
            else { int o2 = oo - 672; d = o2 / 30; k = 21 + o2 % 30; }
            fidx[s] = (((k >> 4) * 64 + ((k & 15) | ((d >> 3) << 4))) << 3) | (d & 7);
            tacc0[s] = 0.f; tacc1[s] = 0.f;
        }
        const uint4* wbase = ((const uint4*)Wlin2) + t;
        #pragma unroll 4
        for (int c = 0; c < DH; ++c) {
            float ac0 = al[0][c], ac1 = al[1][c];
            uint4 wq = wbase[c * 256];
            float wv[7];
            wv[0] = __uint_as_float(wq.x << 16);
            wv[1] = __uint_as_float(wq.x & 0xffff0000u);
            wv[2] = __uint_as_float(wq.y << 16);
            wv[3] = __uint_as_float(wq.y & 0xffff0000u);
            wv[4] = __uint_as_float(wq.z << 16);
            wv[5] = __uint_as_float(wq.z & 0xffff0000u);
            wv[6] = __uint_as_float(wq.w << 16);
            #pragma unroll
            for (int s = 0; s < 7; ++s) {
                tacc0[s] = fmaf(ac0, wv[s], tacc0[s]);
                tacc1[s] = fmaf(ac1, wv[s], tacc1[s]);
            }
        }
        #pragma unroll
        for (int s = 0; s < 7; ++s) {
            if (val[s]) {
                Tf[fidx[s]]        = f2bf(tacc0[s]);
                Tf[2048 + fidx[s]] = f2bf(tacc1[s]);
            }
        }
    }
    __syncthreads();

    // ---- phase 2/3: per-row MFMA + stage + copyout (verified) ----
    const int r  = w >> 1;            // wave's row within pair
    const int mh = w & 1;             // m-half

    bf16x8 afr[4], bfr[4];
    #pragma unroll
    for (int i = 0; i < 4; ++i)
        afr[i] = ((const bf16x8*)bbf)[batch * 512 + (mh * 4 + i) * 64 + l];
    #pragma unroll
    for (int kt = 0; kt < 4; ++kt)
        bfr[kt] = ((const bf16x8*)Tf)[(r * 4 + kt) * 64 + l];

    float bias[4];
    #pragma unroll
    for (int kt = 0; kt < 4; ++kt) {
        int k = kt * 16 + li;
        bias[kt] = (k < K1) ? b1v[k] : (k < KT ? b2v[k - K1] : 0.f);
    }

    #pragma unroll
    for (int rr = 0; rr < 2; ++rr) {
        if (r == rr) {
            #pragma unroll
            for (int i = 0; i < 4; ++i) {
                const int mbase = (mh * 4 + i) * 16 + lg * 4;
                #pragma unroll
                for (int kt = 0; kt < 4; ++kt) {
                    f32x4 acc = __builtin_amdgcn_mfma_f32_16x16x32_bf16(
                        afr[i], bfr[kt], (f32x4){0.f, 0.f, 0.f, 0.f}, 0, 0, 0);
                    const int k = kt * 16 + li;
                    if (k < K1) {
                        #pragma unroll
                        for (int q = 0; q < 4; ++q)
                            stg[(mbase + q) * K1 + k] = acc[q] + bias[kt];
                    } else if (k < KT) {
                        #pragma unroll
                        for (int q = 0; q < 4; ++q)
                            stg[OUT1_ROW + (mbase + q) * K2 + (k - K1)] = acc[q] + bias[kt];
                    }
                }
            }
        }
        __syncthreads();

        const int row = row0 + rr;
        float* o1 = out + (size_t)row * OUT1_ROW;
        float* o2 = out + (size_t)ROWS * OUT1_ROW + (size_t)row * OUT2_ROW;
        const float4* s1 = (const float4*)stg;
        const float4* s2 = (const float4*)(stg + OUT1_ROW);
        for (int i4 = t; i4 < OUT1_ROW / 4; i4 += 256)
            ((float4*)o1)[i4] = s1[i4];
        for (int i4 = t; i4 < OUT2_ROW / 4; i4 += 256)
            ((float4*)o2)[i4] = s2[i4];
        if (rr == 0) __syncthreads();   // stg reused by row 1
    }
}

extern "C" void kernel_launch(void* const* d_in, const int* in_sizes, int n_in,
                              void* d_out, int out_size, void* d_ws, size_t ws_size,
                              hipStream_t stream) {
    const float* z    = (const float*)d_in[0];
    const float* W_in = (const float*)d_in[1];
    const float* b_in = (const float*)d_in[2];
    const float* ln_g = (const float*)d_in[3];
    const float* ln_b = (const float*)d_in[4];
    const float* W1   = (const float*)d_in[5];
    const float* b1   = (const float*)d_in[6];
    const float* W2   = (const float*)d_in[7];
    const float* b2   = (const float*)d_in[8];
    float* out = (float*)d_out;

    float*          a_ws  = (float*)d_ws;                    // 32768 f32 (128 KB)
    unsigned short* bbf   = (unsigned short*)(a_ws + 32768); // 32768 hw (64 KB)
    unsigned short* Wlin2 = bbf + 32768;                     // 65536 hw (128 KB)

    // DIAGNOSTIC: K1 launched twice (idempotent — pure function of d_in).
    // dur(R21) - dur(R20) ~= standalone K1 cost, completing the budget split.
    ln_wprep_kernel<<<ROWS / 2, 256, 0, stream>>>(z, W_in, b_in, ln_g, ln_b,
                                                  W1, W2, a_ws, bbf, Wlin2);
    ln_wprep_kernel<<<ROWS / 2, 256, 0, stream>>>(z, W_in, b_in, ln_g, ln_b,
                                                  W1, W2, a_ws, bbf, Wlin2);
    pair_kernel<<<ROWS / 2, 256, 0, stream>>>(a_ws, bbf, Wlin2, b1, b2, out);
}

// Round 22
// 23.430 us; speedup vs baseline: 1.0872x; 1.0872x over previous
//
#include <hip/hip_runtime.h>
#include <hip/hip_bf16.h>
#include <math.h>

#define NB 8
#define NL 128
#define D_ATOM 256
#define DH 32       // d_hid
#define DAB 64      // 2*d_hid
#define K1 21
#define K2 30
#define KT 51       // K1+K2
#define ROWS (NB*NL) // 1024
#define LN_EPS 1e-5f

#define OUT1_ROW (NL*K1)      // 2688 floats
#define OUT2_ROW (NL*K2)      // 3840 floats
#define STAGE_N  (OUT1_ROW + OUT2_ROW) // 6528 floats
#define TROW_HW 2048          // per-row T fragments: 4 kt * 512 hw

typedef __attribute__((ext_vector_type(8))) short bf16x8;
typedef __attribute__((ext_vector_type(4))) float f32x4;

__device__ __forceinline__ unsigned short f2bf(float x) {
    __hip_bfloat16 h = __float2bfloat16(x);
    return *reinterpret_cast<unsigned short*>(&h);
}

// ---------------- Kernel 1: LN (R20-verified front) + T-GEMV + Tf copyout ----
// 512 blocks x 256 thr, 2 rows/block (same row pairs as K2).
// 1. vectorized z-GEMV (R20 verbatim) -> LN epilogue: a -> al LDS, b -> bbf.
// 2. T-GEMV (R5-verified 7-stream f32 W) -> Tst LDS scatter (verified fidx).
// 3. coalesced uint4 copyout Tst -> T_ws (R11-verified mechanics).
__global__ __launch_bounds__(256) void ln_t_kernel(
    const float* __restrict__ z, const float* __restrict__ W_in,
    const float* __restrict__ b_in, const float* __restrict__ ln_g,
    const float* __restrict__ ln_b, const float* __restrict__ W1,
    const float* __restrict__ W2, unsigned short* __restrict__ bbf,
    unsigned short* __restrict__ T_ws)
{
    __shared__ float zT[D_ATOM][2];        // 2 KB
    __shared__ float red[16][2][DAB];      // 8 KB
    __shared__ float al[2][DH];            // 256 B
    __shared__ unsigned short Tst[2 * TROW_HW]; // 8 KB

    const int t = threadIdx.x;
    const int w = t >> 6, l = t & 63;
    const int g = l >> 4, c4 = l & 15;
    const int row0 = blockIdx.x * 2;

    if (t < 128) {
        const int r = t >> 6, i0 = (t & 63) * 4;
        float4 v = ((const float4*)(z + (size_t)(row0 + r) * D_ATOM))[t & 63];
        zT[i0 + 0][r] = v.x; zT[i0 + 1][r] = v.y;
        zT[i0 + 2][r] = v.z; zT[i0 + 3][r] = v.w;
    }
    __syncthreads();

    // ---- z-GEMV (R20 verbatim) ----
    float acc[2][4];
    #pragma unroll
    for (int r = 0; r < 2; ++r)
        #pragma unroll
        for (int q = 0; q < 4; ++q) acc[r][q] = 0.f;

    const int ibase = w * 64 + g * 16;
    #pragma unroll
    for (int it = 0; it < 16; ++it) {
        const int i = ibase + it;
        float4 wv = *(const float4*)&W_in[i * DAB + 4 * c4];
        float2 zv = *(const float2*)&zT[i][0];
        float wq[4] = {wv.x, wv.y, wv.z, wv.w};
        #pragma unroll
        for (int q = 0; q < 4; ++q) {
            acc[0][q] = fmaf(zv.x, wq[q], acc[0][q]);
            acc[1][q] = fmaf(zv.y, wq[q], acc[1][q]);
        }
    }
    const int p = w * 4 + g;
    #pragma unroll
    for (int r = 0; r < 2; ++r) {
        float4 v = {acc[r][0], acc[r][1], acc[r][2], acc[r][3]};
        *(float4*)&red[p][r][4 * c4] = v;
    }
    __syncthreads();

    // ---- reduce + LN epilogue (verified math) ----
    if (t < 128) {
        const int r = t >> 6, j = t & 63;
        float a2 = b_in[j];
        #pragma unroll
        for (int pp = 0; pp < 16; ++pp) a2 += red[pp][r][j];

        float gg = 0.5f * a2 * (1.0f + erff(a2 * 0.70710678118654752f));

        float s = gg, sq = gg * gg;
        #pragma unroll
        for (int msk = 1; msk < 64; msk <<= 1) {
            s  += __shfl_xor(s,  msk, 64);
            sq += __shfl_xor(sq, msk, 64);
        }
        float mu  = s  * (1.0f / 64.0f);
        float var = sq * (1.0f / 64.0f) - mu * mu;
        float y = (gg - mu) * rsqrtf(var + LN_EPS) * ln_g[j] + ln_b[j];

        const int row = row0 + r;
        if (j < DH) {
            al[r][j] = y;                  // a stays in-block
        } else {
            const int d = j - DH, m = row & 127, batch = row >> 7;
            bbf[batch * 4096 + ((m >> 4) << 9) +
                ((((m & 15) | ((d >> 3) << 4)) << 3) | (d & 7))] = f2bf(y);
        }
    }
    __syncthreads();

    // ---- T-GEMV (R5-verified phase-1, f32 W, 7 coalesced streams) ----
    {
        float tacc0[7], tacc1[7];
        const float* wptr[7];
        int wstr[7], fidx[7];
        bool val[7];
        #pragma unroll
        for (int s = 0; s < 7; ++s) {
            int o = t + s * 256;
            val[s] = (o < 1632);
            int oo = val[s] ? o : 0;
            int d, k;
            if (oo < 672) {
                wptr[s] = W1 + oo; wstr[s] = 672;
                d = oo / 21; k = oo % 21;
            } else {
                int o2 = oo - 672;
                wptr[s] = W2 + o2; wstr[s] = 960;
                d = o2 / 30; k = 21 + o2 % 30;
            }
            fidx[s] = (((k >> 4) * 64 + ((k & 15) | ((d >> 3) << 4))) << 3) | (d & 7);
            tacc0[s] = 0.f; tacc1[s] = 0.f;
        }
        #pragma unroll 4
        for (int c = 0; c < DH; ++c) {
            float ac0 = al[0][c], ac1 = al[1][c];
            #pragma unroll
            for (int s = 0; s < 7; ++s) {
                float wv = wptr[s][c * wstr[s]];
                tacc0[s] = fmaf(ac0, wv, tacc0[s]);
                tacc1[s] = fmaf(ac1, wv, tacc1[s]);
            }
        }
        #pragma unroll
        for (int s = 0; s < 7; ++s) {
            if (val[s]) {
                Tst[fidx[s]]           = f2bf(tacc0[s]);
                Tst[TROW_HW + fidx[s]] = f2bf(tacc1[s]);
            }
        }
    }
    __syncthreads();

    // ---- coalesced copyout: 2 rows x 2048 hw = 512 uint4 (R11-verified) ----
    uint4* dst = (uint4*)(T_ws + (size_t)row0 * TROW_HW);
    const uint4* src = (const uint4*)Tst;
    dst[t]       = src[t];
    dst[t + 256] = src[t + 256];
}

// ---------------- Kernel 2: pair product, NO phase 1 (all pieces verified) ---
// 2 rows per block, 512 blocks. LDS = stg 25.5 KB only.
// Fragments straight from ws (R9-verified source); kt=3 pad lanes masked;
// phase 2/3 = R13 best-verified (single-row stg + coalesced copyout).
__global__ __launch_bounds__(256, 4) void pair_kernel(
    const unsigned short* __restrict__ bbf, const unsigned short* __restrict__ T_ws,
    const float* __restrict__ b1v, const float* __restrict__ b2v,
    float* __restrict__ out)
{
    const int row0  = blockIdx.x * 2;
    const int batch = row0 >> 7;
    const int t     = threadIdx.x;
    const int w = t >> 6, l = t & 63;
    const int lg = l >> 4, li = l & 15;
    const int r = w >> 1;               // wave's row within pair
    const int mh = w & 1;               // m-half

    __shared__ __align__(16) float stg[STAGE_N];   // 25.5 KB

    bf16x8 afr[4], bfr[4];
    #pragma unroll
    for (int i = 0; i < 4; ++i)
        afr[i] = ((const bf16x8*)bbf)[batch * 512 + (mh * 4 + i) * 64 + l];
    #pragma unroll
    for (int kt = 0; kt < 4; ++kt)
        bfr[kt] = ((const bf16x8*)T_ws)[(size_t)(row0 + r) * 256 + kt * 64 + l];

    // kt=3 tile: lanes with k = 48+li >= 51 hold unwritten ws -> zero them.
    if (li >= 3) {
        bf16x8 zz = {0, 0, 0, 0, 0, 0, 0, 0};
        bfr[3] = zz;
    }

    float bias[4];
    #pragma unroll
    for (int kt = 0; kt < 4; ++kt) {
        int k = kt * 16 + li;
        bias[kt] = (k < K1) ? b1v[k] : (k < KT ? b2v[k - K1] : 0.f);
    }

    #pragma unroll
    for (int rr = 0; rr < 2; ++rr) {
        if (r == rr) {
            #pragma unroll
            for (int i = 0; i < 4; ++i) {
                const int mbase = (mh * 4 + i) * 16 + lg * 4;
                #pragma unroll
                for (int kt = 0; kt < 4; ++kt) {
                    f32x4 acc = __builtin_amdgcn_mfma_f32_16x16x32_bf16(
                        afr[i], bfr[kt], (f32x4){0.f, 0.f, 0.f, 0.f}, 0, 0, 0);
                    const int k = kt * 16 + li;
                    if (k < K1) {
                        #pragma unroll
                        for (int q = 0; q < 4; ++q)
                            stg[(mbase + q) * K1 + k] = acc[q] + bias[kt];
                    } else if (k < KT) {
                        #pragma unroll
                        for (int q = 0; q < 4; ++q)
                            stg[OUT1_ROW + (mbase + q) * K2 + (k - K1)] = acc[q] + bias[kt];
                    }
                }
            }
        }
        __syncthreads();

        const int row = row0 + rr;
        float* o1 = out + (size_t)row * OUT1_ROW;
        float* o2 = out + (size_t)ROWS * OUT1_ROW + (size_t)row * OUT2_ROW;
        const float4* s1 = (const float4*)stg;
        const float4* s2 = (const float4*)(stg + OUT1_ROW);
        for (int i4 = t; i4 < OUT1_ROW / 4; i4 += 256)
            ((float4*)o1)[i4] = s1[i4];
        for (int i4 = t; i4 < OUT2_ROW / 4; i4 += 256)
            ((float4*)o2)[i4] = s2[i4];
        if (rr == 0) __syncthreads();   // stg reused by row 1
    }
}

extern "C" void kernel_launch(void* const* d_in, const int* in_sizes, int n_in,
                              void* d_out, int out_size, void* d_ws, size_t ws_size,
                              hipStream_t stream) {
    const float* z    = (const float*)d_in[0];
    const float* W_in = (const float*)d_in[1];
    const float* b_in = (const float*)d_in[2];
    const float* ln_g = (const float*)d_in[3];
    const float* ln_b = (const float*)d_in[4];
    const float* W1   = (const float*)d_in[5];
    const float* b1   = (const float*)d_in[6];
    const float* W2   = (const float*)d_in[7];
    const float* b2   = (const float*)d_in[8];
    float* out = (float*)d_out;

    unsigned short* bbf  = (unsigned short*)d_ws;   // 32768 hw (64 KB)
    unsigned short* T_ws = bbf + 32768;             // 1024*2048 hw (4 MB)

    ln_t_kernel<<<ROWS / 2, 256, 0, stream>>>(z, W_in, b_in, ln_g, ln_b,
                                              W1, W2, bbf, T_ws);
    pair_kernel<<<ROWS / 2, 256, 0, stream>>>(bbf, T_ws, b1, b2, out);
}

// Round 23
// 21.342 us; speedup vs baseline: 1.1936x; 1.0978x over previous
//
#include <hip/hip_runtime.h>
#include <hip/hip_bf16.h>
#include <math.h>

#define NB 8
#define NL 128
#define D_ATOM 256
#define DH 32       // d_hid
#define DAB 64      // 2*d_hid
#define K1 21
#define K2 30
#define KT 51       // K1+K2
#define ROWS (NB*NL) // 1024
#define LN_EPS 1e-5f

#define OUT1_ROW (NL*K1)      // 2688 floats
#define OUT2_ROW (NL*K2)      // 3840 floats
#define STAGE_N  (OUT1_ROW + OUT2_ROW) // 6528 floats
#define WCAT 1632             // 672 + 960 els per c

typedef __attribute__((ext_vector_type(8))) short bf16x8;
typedef __attribute__((ext_vector_type(4))) float f32x4;

__device__ __forceinline__ unsigned short f2bf(float x) {
    __hip_bfloat16 h = __float2bfloat16(x);
    return *reinterpret_cast<unsigned short*>(&h);
}

// ---------------- Kernel 1: LN v3 (R20 verbatim — best measured) ------------
// 512 blocks x 256 thr, 2 rows/block. GEMV direct from L2 (float4), 16-way
// K-split, LDS partial reduce; LN epilogue; folded Wlin2 prep (16 uint4/block).
__global__ __launch_bounds__(256) void ln_wprep_kernel(
    const float* __restrict__ z, const float* __restrict__ W_in,
    const float* __restrict__ b_in, const float* __restrict__ ln_g,
    const float* __restrict__ ln_b, const float* __restrict__ W1,
    const float* __restrict__ W2, float* __restrict__ a_ws,
    unsigned short* __restrict__ bbf, unsigned short* __restrict__ Wlin2)
{
    __shared__ float zT[D_ATOM][2];      // 2 KB: zT[i][r]
    __shared__ float red[16][2][DAB];    // 8 KB partials [p][r][col]

    const int t = threadIdx.x;
    const int w = t >> 6, l = t & 63;
    const int g = l >> 4, c4 = l & 15;
    const int row0 = blockIdx.x * 2;

    if (t < 128) {
        const int r = t >> 6, i0 = (t & 63) * 4;
        float4 v = ((const float4*)(z + (size_t)(row0 + r) * D_ATOM))[t & 63];
        zT[i0 + 0][r] = v.x; zT[i0 + 1][r] = v.y;
        zT[i0 + 2][r] = v.z; zT[i0 + 3][r] = v.w;
    }
    __syncthreads();

    float acc[2][4];
    #pragma unroll
    for (int r = 0; r < 2; ++r)
        #pragma unroll
        for (int q = 0; q < 4; ++q) acc[r][q] = 0.f;

    const int ibase = w * 64 + g * 16;
    #pragma unroll
    for (int it = 0; it < 16; ++it) {
        const int i = ibase + it;
        float4 wv = *(const float4*)&W_in[i * DAB + 4 * c4];
        float2 zv = *(const float2*)&zT[i][0];
        float wq[4] = {wv.x, wv.y, wv.z, wv.w};
        #pragma unroll
        for (int q = 0; q < 4; ++q) {
            acc[0][q] = fmaf(zv.x, wq[q], acc[0][q]);
            acc[1][q] = fmaf(zv.y, wq[q], acc[1][q]);
        }
    }
    const int p = w * 4 + g;
    #pragma unroll
    for (int r = 0; r < 2; ++r) {
        float4 v = {acc[r][0], acc[r][1], acc[r][2], acc[r][3]};
        *(float4*)&red[p][r][4 * c4] = v;
    }
    __syncthreads();

    if (t < 128) {
        const int r = t >> 6, j = t & 63;
        float a2 = b_in[j];
        #pragma unroll
        for (int pp = 0; pp < 16; ++pp) a2 += red[pp][r][j];

        float gg = 0.5f * a2 * (1.0f + erff(a2 * 0.70710678118654752f));

        float s = gg, sq = gg * gg;
        #pragma unroll
        for (int msk = 1; msk < 64; msk <<= 1) {
            s  += __shfl_xor(s,  msk, 64);
            sq += __shfl_xor(sq, msk, 64);
        }
        float mu  = s  * (1.0f / 64.0f);
        float var = sq * (1.0f / 64.0f) - mu * mu;
        float y = (gg - mu) * rsqrtf(var + LN_EPS) * ln_g[j] + ln_b[j];

        const int row = row0 + r;
        if (j < DH) {
            a_ws[row * DH + j] = y;
        } else {
            const int d = j - DH, m = row & 127, batch = row >> 7;
            bbf[batch * 4096 + ((m >> 4) << 9) +
                ((((m & 15) | ((d >> 3) << 4)) << 3) | (d & 7))] = f2bf(y);
        }
    }

    if (t < 16) {
        int pw = (int)blockIdx.x * 16 + t;      // 0..8191
        int c  = pw >> 8, t2 = pw & 255;
        unsigned short v[8];
        #pragma unroll
        for (int s2 = 0; s2 < 8; ++s2) {
            int o = s2 * 256 + t2;
            float val = 0.f;
            if (o < 672)       val = W1[c * 672 + o];
            else if (o < WCAT) val = W2[c * 960 + (o - 672)];
            v[s2] = f2bf(val);
        }
        uint4 wq;
        wq.x = (unsigned)v[0] | ((unsigned)v[1] << 16);
        wq.y = (unsigned)v[2] | ((unsigned)v[3] << 16);
        wq.z = (unsigned)v[4] | ((unsigned)v[5] << 16);
        wq.w = (unsigned)v[6] | ((unsigned)v[7] << 16);
        ((uint4*)Wlin2)[pw] = wq;
    }
}

// ---------------- Kernel 2: pair product (R13/R17 verbatim — best) ----------
// 2 rows per block, 512 blocks, 34.6 KB LDS.
// Phase 1: T GEMV (uint4-packed bf16 Wlin2). Phase 2: 16 MFMA/wave.
// Phase 3: single-row LDS stage + fully-coalesced float4 copyout.
__global__ __launch_bounds__(256, 4) void pair_kernel(
    const float* __restrict__ a_ws, const unsigned short* __restrict__ bbf,
    const unsigned short* __restrict__ Wlin2, const float* __restrict__ b1v,
    const float* __restrict__ b2v, float* __restrict__ out)
{
    const int row0  = blockIdx.x * 2;
    const int batch = row0 >> 7;
    const int t     = threadIdx.x;
    const int w  = t >> 6, l = t & 63;
    const int lg = l >> 4, li = l & 15;

    __shared__ unsigned short Tf[2 * 4 * 64 * 8];    // 8 KB
    __shared__ __align__(16) float stg[STAGE_N];     // 25.5 KB (one row)
    __shared__ float al[2][DH];

    #pragma unroll
    for (int s = 0; s < 8; ++s)
        ((unsigned int*)Tf)[t + s * 256] = 0u;       // pads k=51..63 stay 0
    if (t < 2 * DH) al[t >> 5][t & 31] = a_ws[row0 * DH + t];
    __syncthreads();

    // ---- phase 1: T GEMV (uint4-packed Wlin2) ----
    {
        float tacc0[7], tacc1[7];
        int fidx[7];
        bool val[7];
        #pragma unroll
        for (int s = 0; s < 7; ++s) {
            int o = t + s * 256;
            val[s] = (o < WCAT);
            int oo = val[s] ? o : 0;
            int d, k;
            if (oo < 672) { d = oo / 21; k = oo % 21; }
            else { int o2 = oo - 672; d = o2 / 30; k = 21 + o2 % 30; }
            fidx[s] = (((k >> 4) * 64 + ((k & 15) | ((d >> 3) << 4))) << 3) | (d & 7);
            tacc0[s] = 0.f; tacc1[s] = 0.f;
        }
        const uint4* wbase = ((const uint4*)Wlin2) + t;
        #pragma unroll 4
        for (int c = 0; c < DH; ++c) {
            float ac0 = al[0][c], ac1 = al[1][c];
            uint4 wq = wbase[c * 256];
            float wv[7];
            wv[0] = __uint_as_float(wq.x << 16);
            wv[1] = __uint_as_float(wq.x & 0xffff0000u);
            wv[2] = __uint_as_float(wq.y << 16);
            wv[3] = __uint_as_float(wq.y & 0xffff0000u);
            wv[4] = __uint_as_float(wq.z << 16);
            wv[5] = __uint_as_float(wq.z & 0xffff0000u);
            wv[6] = __uint_as_float(wq.w << 16);
            #pragma unroll
            for (int s = 0; s < 7; ++s) {
                tacc0[s] = fmaf(ac0, wv[s], tacc0[s]);
                tacc1[s] = fmaf(ac1, wv[s], tacc1[s]);
            }
        }
        #pragma unroll
        for (int s = 0; s < 7; ++s) {
            if (val[s]) {
                Tf[fidx[s]]        = f2bf(tacc0[s]);
                Tf[2048 + fidx[s]] = f2bf(tacc1[s]);
            }
        }
    }
    __syncthreads();

    // ---- phase 2/3: per-row MFMA + stage + copyout (verified) ----
    const int r  = w >> 1;            // wave's row within pair
    const int mh = w & 1;             // m-half

    bf16x8 afr[4], bfr[4];
    #pragma unroll
    for (int i = 0; i < 4; ++i)
        afr[i] = ((const bf16x8*)bbf)[batch * 512 + (mh * 4 + i) * 64 + l];
    #pragma unroll
    for (int kt = 0; kt < 4; ++kt)
        bfr[kt] = ((const bf16x8*)Tf)[(r * 4 + kt) * 64 + l];

    float bias[4];
    #pragma unroll
    for (int kt = 0; kt < 4; ++kt) {
        int k = kt * 16 + li;
        bias[kt] = (k < K1) ? b1v[k] : (k < KT ? b2v[k - K1] : 0.f);
    }

    #pragma unroll
    for (int rr = 0; rr < 2; ++rr) {
        if (r == rr) {
            #pragma unroll
            for (int i = 0; i < 4; ++i) {
                const int mbase = (mh * 4 + i) * 16 + lg * 4;
                #pragma unroll
                for (int kt = 0; kt < 4; ++kt) {
                    f32x4 acc = __builtin_amdgcn_mfma_f32_16x16x32_bf16(
                        afr[i], bfr[kt], (f32x4){0.f, 0.f, 0.f, 0.f}, 0, 0, 0);
                    const int k = kt * 16 + li;
                    if (k < K1) {
                        #pragma unroll
                        for (int q = 0; q < 4; ++q)
                            stg[(mbase + q) * K1 + k] = acc[q] + bias[kt];
                    } else if (k < KT) {
                        #pragma unroll
                        for (int q = 0; q < 4; ++q)
                            stg[OUT1_ROW + (mbase + q) * K2 + (k - K1)] = acc[q] + bias[kt];
                    }
                }
            }
        }
        __syncthreads();

        const int row = row0 + rr;
        float* o1 = out + (size_t)row * OUT1_ROW;
        float* o2 = out + (size_t)ROWS * OUT1_ROW + (size_t)row * OUT2_ROW;
        const float4* s1 = (const float4*)stg;
        const float4* s2 = (const float4*)(stg + OUT1_ROW);
        for (int i4 = t; i4 < OUT1_ROW / 4; i4 += 256)
            ((float4*)o1)[i4] = s1[i4];
        for (int i4 = t; i4 < OUT2_ROW / 4; i4 += 256)
            ((float4*)o2)[i4] = s2[i4];
        if (rr == 0) __syncthreads();   // stg reused by row 1
    }
}

extern "C" void kernel_launch(void* const* d_in, const int* in_sizes, int n_in,
                              void* d_out, int out_size, void* d_ws, size_t ws_size,
                              hipStream_t stream) {
    const float* z    = (const float*)d_in[0];
    const float* W_in = (const float*)d_in[1];
    const float* b_in = (const float*)d_in[2];
    const float* ln_g = (const float*)d_in[3];
    const float* ln_b = (const float*)d_in[4];
    const float* W1   = (const float*)d_in[5];
    const float* b1   = (const float*)d_in[6];
    const float* W2   = (const float*)d_in[7];
    const float* b2   = (const float*)d_in[8];
    float* out = (float*)d_out;

    float*          a_ws  = (float*)d_ws;                    // 32768 f32 (128 KB)
    unsigned short* bbf   = (unsigned short*)(a_ws + 32768); // 32768 hw (64 KB)
    unsigned short* Wlin2 = bbf + 32768;                     // 65536 hw (128 KB)

    ln_wprep_kernel<<<ROWS / 2, 256, 0, stream>>>(z, W_in, b_in, ln_g, ln_b,
                                                  W1, W2, a_ws, bbf, Wlin2);
    pair_kernel<<<ROWS / 2, 256, 0, stream>>>(a_ws, bbf, Wlin2, b1, b2, out);
}